// Round 1
// baseline (732.201 us; speedup 1.0000x reference)
//
#include <hip/hip_runtime.h>
#include <math.h>

// GATLayerEdgeSoftmax: o = seg_sum(y*e, tgt) / (seg_sum(e, tgt) + eps)
//   y = relu(u[src] + v[tgt] + bf),  e = exp((p[src]+q[tgt]) - max_e(p+q))
//   u = x @ Wf[:, :64].T, v = x @ Wf[:, 64:].T, p = x @ Ww[:64], q = x @ Ww[64:]
// (bw cancels exactly inside exp(a - amax); bf does not and is applied.)

#define DID 64   // DI
#define DOD 64   // DO

// ---- monotone float<->uint key for atomicMax on floats ----
__device__ __forceinline__ unsigned f2key(float f) {
  unsigned u = __float_as_uint(f);
  return (u & 0x80000000u) ? ~u : (u | 0x80000000u);
}
__device__ __forceinline__ float key2f(unsigned k) {
  unsigned u = (k & 0x80000000u) ? (k ^ 0x80000000u) : ~k;
  return __uint_as_float(u);
}

// ---- kernel 1: per-node projections u,v [N,64] and p,q [N] ----
__global__ __launch_bounds__(256) void node_uv_kernel(
    const float* __restrict__ x, const float* __restrict__ Wf,
    const float* __restrict__ Ww, int N,
    float* __restrict__ u, float* __restrict__ v,
    float* __restrict__ p, float* __restrict__ q) {
  // WA[k][j] = Wf[j][k] (k<64), WB[k][j] = Wf[j][64+k]  (transposed for
  // conflict-free ds_read: lane j reads consecutive addresses)
  __shared__ float WA[64 * 64];
  __shared__ float WB[64 * 64];
  __shared__ float Ws[64];
  __shared__ float Wt[64];
  for (int idx = threadIdx.x; idx < 64 * 128; idx += 256) {
    int j = idx >> 7, kk = idx & 127;
    float w = Wf[idx];
    if (kk < 64) WA[kk * 64 + j] = w;
    else         WB[(kk - 64) * 64 + j] = w;
  }
  if (threadIdx.x < 128) {
    float w = Ww[threadIdx.x];
    if (threadIdx.x < 64) Ws[threadIdx.x] = w;
    else                  Wt[threadIdx.x - 64] = w;
  }
  __syncthreads();

  const int lane   = threadIdx.x & 63;
  const int wid    = blockIdx.x * (blockDim.x >> 6) + (threadIdx.x >> 6);
  const int nwaves = gridDim.x * (blockDim.x >> 6);

  for (int n = wid; n < N; n += nwaves) {
    float xl = x[(size_t)n * DID + lane];

    // p,q: per-lane partial then butterfly reduce
    float pp = xl * Ws[lane];
    float qq = xl * Wt[lane];
    #pragma unroll
    for (int o = 32; o >= 1; o >>= 1) {
      pp += __shfl_xor(pp, o);
      qq += __shfl_xor(qq, o);
    }

    float uu = 0.f, vv = 0.f;
    #pragma unroll
    for (int k = 0; k < 64; ++k) {
      float xb = __shfl(xl, k);       // broadcast x[n][k] (readlane)
      uu += WA[k * 64 + lane] * xb;
      vv += WB[k * 64 + lane] * xb;
    }
    u[(size_t)n * DOD + lane] = uu;
    v[(size_t)n * DOD + lane] = vv;
    if (lane == 0) { p[n] = pp; q[n] = qq; }
  }
}

// ---- kernel 2: global max of (p[src]+q[tgt]) ----
__global__ __launch_bounds__(256) void edge_amax_kernel(
    const int* __restrict__ src, const int* __restrict__ tgt,
    const float* __restrict__ p, const float* __restrict__ q,
    int E, unsigned* __restrict__ amax_key) {
  float m = -INFINITY;
  int tid = blockIdx.x * blockDim.x + threadIdx.x;
  int stride = gridDim.x * blockDim.x;
  for (int e = tid; e < E; e += stride) {
    m = fmaxf(m, p[src[e]] + q[tgt[e]]);
  }
  #pragma unroll
  for (int o = 32; o >= 1; o >>= 1) m = fmaxf(m, __shfl_xor(m, o));
  if ((threadIdx.x & 63) == 0) atomicMax(amax_key, f2key(m));
}

// ---- kernel 3: per-edge scatter: onum[tgt] += y*e, asum[tgt] += e ----
__global__ __launch_bounds__(256) void edge_scatter_kernel(
    const int* __restrict__ src, const int* __restrict__ tgt,
    const float* __restrict__ p, const float* __restrict__ q,
    const float* __restrict__ u, const float* __restrict__ v,
    const float* __restrict__ bf, const unsigned* __restrict__ amax_key,
    int E, float* __restrict__ onum, float* __restrict__ asum) {
  const int lane   = threadIdx.x & 63;
  const int wid    = blockIdx.x * (blockDim.x >> 6) + (threadIdx.x >> 6);
  const int nwaves = gridDim.x * (blockDim.x >> 6);
  const float amax = key2f(*amax_key);
  const float bfl  = bf[lane];

  for (int e = wid; e < E; e += nwaves) {
    int s = src[e];   // uniform per wave -> scalar load
    int t = tgt[e];
    float w = __expf(p[s] + q[t] - amax);
    float y = fmaxf(u[(size_t)s * DOD + lane] + v[(size_t)t * DOD + lane] + bfl,
                    0.f) * w;
    unsafeAtomicAdd(&onum[(size_t)t * DOD + lane], y);
    if (lane == 0) unsafeAtomicAdd(&asum[t], w);
  }
}

// ---- kernel 4: o = onum / (asum + eps), in place on d_out ----
__global__ __launch_bounds__(256) void finalize_kernel(
    float* __restrict__ o, const float* __restrict__ asum, int N) {
  int idx = blockIdx.x * blockDim.x + threadIdx.x;
  if (idx < N * DOD) {
    o[idx] = o[idx] / (asum[idx >> 6] + 1e-6f);
  }
}

extern "C" void kernel_launch(void* const* d_in, const int* in_sizes, int n_in,
                              void* d_out, int out_size, void* d_ws, size_t ws_size,
                              hipStream_t stream) {
  const float* x   = (const float*)d_in[0];   // [N,64]
  const float* Wf  = (const float*)d_in[1];   // [64,128]
  const float* bf  = (const float*)d_in[2];   // [64]
  const float* Ww  = (const float*)d_in[3];   // [1,128]
  // d_in[4] = bw: cancels inside exp(a - amax); bw itself shifts num & denom
  // weights identically, so unused.
  const int* src   = (const int*)d_in[5];     // [E]
  const int* tgt   = (const int*)d_in[6];     // [E]

  const int N = in_sizes[0] / DID;
  const int E = in_sizes[5];

  // workspace layout (fp32): u[N*64] v[N*64] p[N] q[N] asum[N] amax_key[1]
  float* u = (float*)d_ws;
  float* v = u + (size_t)N * DOD;
  float* p = v + (size_t)N * DOD;
  float* q = p + N;
  float* asum = q + N;
  unsigned* amax_key = (unsigned*)(asum + N);
  float* onum = (float*)d_out;                // accumulate numerator in d_out

  hipMemsetAsync(d_out, 0, (size_t)N * DOD * sizeof(float), stream);
  hipMemsetAsync(asum, 0, (size_t)N * sizeof(float), stream);
  hipMemsetAsync(amax_key, 0, sizeof(unsigned), stream);

  node_uv_kernel<<<1024, 256, 0, stream>>>(x, Wf, Ww, N, u, v, p, q);
  edge_amax_kernel<<<2048, 256, 0, stream>>>(src, tgt, p, q, E, amax_key);
  edge_scatter_kernel<<<4096, 256, 0, stream>>>(src, tgt, p, q, u, v, bf,
                                                amax_key, E, onum, asum);
  int fin_blocks = (N * DOD + 255) / 256;
  finalize_kernel<<<fin_blocks, 256, 0, stream>>>(onum, asum, N);
}

// Round 6
// 557.654 us; speedup vs baseline: 1.3130x; 1.3130x over previous
//
#include <hip/hip_runtime.h>
#include <math.h>

// GATLayerEdgeSoftmax, CSR-gather formulation:
//   u = x @ Wf[:, :64].T, v = x @ Wf[:, 64:].T, p = x @ Ww[:64], q = x @ Ww[64:]
//   a_e = p[src]+q[tgt]  (bw cancels in exp(a - amax))
//   w_e = exp(a_e - max_e a)
//   o[t] = sum_{e: tgt=t} relu(u[src]+v[t]+bf)*w_e / (sum w_e + eps)
// Pipeline: node_uv -> hist+amax -> 3-kernel scan -> CSR fill (stores (src,w))
//           -> per-node register-accumulated gather (no f32 atomics anywhere).

#define DID 64
#define DOD 64
#define SCAN_CHUNK 1024

__device__ __forceinline__ unsigned f2key(float f) {
  unsigned u = __float_as_uint(f);
  return (u & 0x80000000u) ? ~u : (u | 0x80000000u);
}
__device__ __forceinline__ float key2f(unsigned k) {
  unsigned u = (k & 0x80000000u) ? (k ^ 0x80000000u) : ~k;
  return __uint_as_float(u);
}

// ---- kernel 1: per-node projections. W held in VGPRs (128 regs/lane). ----
__global__ __launch_bounds__(256) void node_uv_kernel(
    const float* __restrict__ x, const float* __restrict__ Wf,
    const float* __restrict__ Ww, int N,
    float* __restrict__ u, float* __restrict__ v,
    float* __restrict__ p, float* __restrict__ q) {
  const int lane = threadIdx.x & 63;
  // lane j needs row j of Wf: Wf[j][k] (k<64 -> wa, k>=64 -> wb), contiguous.
  float wa[64], wb[64];
  const float4* wr = (const float4*)(Wf + (size_t)lane * 128);
  #pragma unroll
  for (int k4 = 0; k4 < 16; ++k4) {
    float4 t = wr[k4];
    wa[k4 * 4 + 0] = t.x; wa[k4 * 4 + 1] = t.y;
    wa[k4 * 4 + 2] = t.z; wa[k4 * 4 + 3] = t.w;
  }
  #pragma unroll
  for (int k4 = 0; k4 < 16; ++k4) {
    float4 t = wr[16 + k4];
    wb[k4 * 4 + 0] = t.x; wb[k4 * 4 + 1] = t.y;
    wb[k4 * 4 + 2] = t.z; wb[k4 * 4 + 3] = t.w;
  }
  const float wsl = Ww[lane];
  const float wtl = Ww[64 + lane];

  const int wid = blockIdx.x * (blockDim.x >> 6) + (threadIdx.x >> 6);
  const int nw  = gridDim.x * (blockDim.x >> 6);
  for (int n = wid; n < N; n += nw) {
    float xl = x[(size_t)n * DID + lane];
    float pp = xl * wsl, qq = xl * wtl;
    #pragma unroll
    for (int o = 32; o >= 1; o >>= 1) {
      pp += __shfl_xor(pp, o);
      qq += __shfl_xor(qq, o);
    }
    float uu = 0.f, vv = 0.f;
    #pragma unroll
    for (int k = 0; k < 64; ++k) {
      float xb = __shfl(xl, k);   // readlane broadcast
      uu = fmaf(xb, wa[k], uu);
      vv = fmaf(xb, wb[k], vv);
    }
    u[(size_t)n * DOD + lane] = uu;
    v[(size_t)n * DOD + lane] = vv;
    if (lane == 0) { p[n] = pp; q[n] = qq; }
  }
}

// ---- kernel 2: degree histogram (by tgt) + global amax, one pass ----
__global__ __launch_bounds__(256) void hist_amax_kernel(
    const int* __restrict__ src, const int* __restrict__ tgt,
    const float* __restrict__ p, const float* __restrict__ q,
    int E, int* __restrict__ hist, unsigned* __restrict__ amax_key) {
  float m = -INFINITY;
  int tid = blockIdx.x * blockDim.x + threadIdx.x;
  int st  = gridDim.x * blockDim.x;
  for (int e = tid; e < E; e += st) {
    int t = tgt[e], s = src[e];
    atomicAdd(&hist[t], 1);
    m = fmaxf(m, p[s] + q[t]);
  }
  #pragma unroll
  for (int o = 32; o >= 1; o >>= 1) m = fmaxf(m, __shfl_xor(m, o));
  if ((threadIdx.x & 63) == 0) atomicMax(amax_key, f2key(m));
}

// ---- scan (3 kernels): exclusive prefix sum of hist -> rowstart ----
__global__ __launch_bounds__(256) void scan1_kernel(
    const int* __restrict__ hist, int* __restrict__ rowstart,
    int* __restrict__ bsum, int N) {
  int base = blockIdx.x * SCAN_CHUNK + threadIdx.x * 4;
  int h[4]; int ts = 0;
  #pragma unroll
  for (int j = 0; j < 4; ++j) {
    int i = base + j;
    h[j] = (i < N) ? hist[i] : 0;
    ts += h[j];
  }
  int lane = threadIdx.x & 63, wv = threadIdx.x >> 6;
  int sc = ts;
  #pragma unroll
  for (int o = 1; o < 64; o <<= 1) {
    int t = __shfl_up(sc, o);
    if (lane >= o) sc += t;
  }
  __shared__ int wtot[4];
  if (lane == 63) wtot[wv] = sc;
  __syncthreads();
  int woff = 0;
  for (int w = 0; w < wv; ++w) woff += wtot[w];
  int excl = woff + sc - ts;
  #pragma unroll
  for (int j = 0; j < 4; ++j) {
    int i = base + j;
    if (i < N) rowstart[i] = excl;
    excl += h[j];
  }
  if (threadIdx.x == 0) {
    int tot = 0;
    for (int w = 0; w < 4; ++w) tot += wtot[w];
    bsum[blockIdx.x] = tot;
  }
}

__global__ __launch_bounds__(256) void scan2_kernel(int* __restrict__ bsum, int SB) {
  __shared__ int tmp[256];
  int t = threadIdx.x;
  int s = (t < SB) ? bsum[t] : 0;
  tmp[t] = s;
  __syncthreads();
  int acc = s;
  for (int o = 1; o < 256; o <<= 1) {
    int vv = (t >= o) ? tmp[t - o] : 0;
    __syncthreads();
    acc += vv;
    tmp[t] = acc;
    __syncthreads();
  }
  if (t < SB) bsum[t] = acc - s;   // exclusive block offset
}

__global__ __launch_bounds__(256) void scan3_kernel(
    int* __restrict__ rowstart, int* __restrict__ cursor,
    const int* __restrict__ bsum, int N, int E) {
  int base = blockIdx.x * SCAN_CHUNK + threadIdx.x * 4;
  int off = bsum[blockIdx.x];
  #pragma unroll
  for (int j = 0; j < 4; ++j) {
    int i = base + j;
    if (i < N) {
      int r = rowstart[i] + off;
      rowstart[i] = r;
      cursor[i] = r;
    }
  }
  if (blockIdx.x == 0 && threadIdx.x == 0) rowstart[N] = E;
}

// ---- kernel: CSR fill — store (src, w=exp(a-amax)) packed 8B per edge ----
__global__ __launch_bounds__(256) void fill_kernel(
    const int* __restrict__ src, const int* __restrict__ tgt,
    const float* __restrict__ p, const float* __restrict__ q,
    const unsigned* __restrict__ amax_key, int E,
    int* __restrict__ cursor, int2* __restrict__ csr) {
  const float amax = key2f(*amax_key);
  int tid = blockIdx.x * blockDim.x + threadIdx.x;
  int st  = gridDim.x * blockDim.x;
  for (int e = tid; e < E; e += st) {
    int t = tgt[e], s = src[e];
    float w = __expf(p[s] + q[t] - amax);
    int pos = atomicAdd(&cursor[t], 1);
    csr[pos] = make_int2(s, __float_as_int(w));
  }
}

// ---- kernel: per-node gather + fused normalize. Wave per node row. ----
__global__ __launch_bounds__(256) void gather_kernel(
    const int* __restrict__ rowstart, const int2* __restrict__ csr,
    const float* __restrict__ u, const float* __restrict__ v,
    const float* __restrict__ bf, int N, float* __restrict__ o) {
  const int lane = threadIdx.x & 63;
  const float bfl = bf[lane];
  const int wid = blockIdx.x * (blockDim.x >> 6) + (threadIdx.x >> 6);
  const int nw  = gridDim.x * (blockDim.x >> 6);
  for (int n = wid; n < N; n += nw) {
    int beg = rowstart[n], end = rowstart[n + 1];
    float vtl = v[(size_t)n * DOD + lane];
    float acc = 0.f, wsum = 0.f;
    for (int i = beg; i < end; ++i) {
      int2 c = csr[i];                       // uniform 8B broadcast load
      float w = __uint_as_float((unsigned)c.y);
      float us = u[(size_t)c.x * DOD + lane]; // 256B coalesced row gather
      wsum += w;
      acc = fmaf(fmaxf(us + vtl + bfl, 0.f), w, acc);
    }
    o[(size_t)n * DOD + lane] = acc / (wsum + 1e-6f);
  }
}

extern "C" void kernel_launch(void* const* d_in, const int* in_sizes, int n_in,
                              void* d_out, int out_size, void* d_ws, size_t ws_size,
                              hipStream_t stream) {
  const float* x  = (const float*)d_in[0];
  const float* Wf = (const float*)d_in[1];
  const float* bf = (const float*)d_in[2];
  const float* Ww = (const float*)d_in[3];
  // d_in[4] = bw (cancels), d_in[7] = num_nodes (derived from sizes)
  const int* src = (const int*)d_in[5];
  const int* tgt = (const int*)d_in[6];

  const int N = in_sizes[0] / DID;
  const int E = in_sizes[5];

  // workspace: csr[E] int2 | u[N*64] | v[N*64] | p[N] | q[N]
  //            | hist[N] | rowstart[N+1] | cursor[N] | bsum[256] | amax_key
  int2*  csr = (int2*)d_ws;
  float* u   = (float*)(csr + E);
  float* v   = u + (size_t)N * DOD;
  float* p   = v + (size_t)N * DOD;
  float* q   = p + N;
  int* hist     = (int*)(q + N);
  int* rowstart = hist + N;          // N+1 entries
  int* cursor   = rowstart + N + 1;
  int* bsum     = cursor + N;        // 256 entries
  unsigned* amax_key = (unsigned*)(bsum + 256);

  hipMemsetAsync(hist, 0, (size_t)N * sizeof(int), stream);
  hipMemsetAsync(amax_key, 0, sizeof(unsigned), stream);

  const int SB = (N + SCAN_CHUNK - 1) / SCAN_CHUNK;   // 98 for N=100K (<=256)

  node_uv_kernel<<<1024, 256, 0, stream>>>(x, Wf, Ww, N, u, v, p, q);
  hist_amax_kernel<<<2048, 256, 0, stream>>>(src, tgt, p, q, E, hist, amax_key);
  scan1_kernel<<<SB, 256, 0, stream>>>(hist, rowstart, bsum, N);
  scan2_kernel<<<1, 256, 0, stream>>>(bsum, SB);
  scan3_kernel<<<SB, 256, 0, stream>>>(rowstart, cursor, bsum, N, E);
  fill_kernel<<<2048, 256, 0, stream>>>(src, tgt, p, q, amax_key, E, cursor, csr);
  gather_kernel<<<2048, 256, 0, stream>>>(rowstart, csr, u, v, bf, N, (float*)d_out);
}

// Round 11
// 481.538 us; speedup vs baseline: 1.5205x; 1.1581x over previous
//
#include <hip/hip_runtime.h>
#include <math.h>

// GATLayerEdgeSoftmax, CSR-gather v3b:
//   u = x @ Wf[:, :64].T, v = x @ Wf[:, 64:].T, p = x @ Ww[:64], q = x @ Ww[64:]
//   Shift by upper bound M = max(p)+max(q); w_e = exp(a_e - M) = c * w_ref,
//   c = exp(amax - M) = wmax (tracked exactly in fill). Gather uses
//   epsEff = eps * wmax:  c·num/(c·den + c·eps) == num/(den + eps)  — exact.
//   (v3 bug: used eps/wmax -> eps inflated by 1/c^2 ≈ 45x -> absmax 0.477.
//    v2 used eps -> 1/c ≈ 11x -> 0.133. Both consistent with this one error.)
// Pipeline: node_uv(+p/q max) -> hist(stream tgt only) -> scan ->
//           fill(int4, ILP-8 gathers, +wmax reduce) -> gather(coalesced csr
//           batch + shuffle broadcast + 4x-unrolled u-row loads, eps*wmax).

#define DID 64
#define DOD 64
#define SCAN_CHUNK 1024

__device__ __forceinline__ unsigned f2key(float f) {
  unsigned u = __float_as_uint(f);
  return (u & 0x80000000u) ? ~u : (u | 0x80000000u);
}
__device__ __forceinline__ float key2f(unsigned k) {
  unsigned u = (k & 0x80000000u) ? (k ^ 0x80000000u) : ~k;
  return __uint_as_float(u);
}

// ---- kernel 1: node projections; W in VGPRs; also reduces max(p), max(q) ----
__global__ __launch_bounds__(256) void node_uv_kernel(
    const float* __restrict__ x, const float* __restrict__ Wf,
    const float* __restrict__ Ww, int N,
    float* __restrict__ u, float* __restrict__ v,
    float* __restrict__ p, float* __restrict__ q,
    unsigned* __restrict__ pqmax_key) {
  const int lane = threadIdx.x & 63;
  float wa[64], wb[64];
  const float4* wr = (const float4*)(Wf + (size_t)lane * 128);
  #pragma unroll
  for (int k4 = 0; k4 < 16; ++k4) {
    float4 t = wr[k4];
    wa[k4 * 4 + 0] = t.x; wa[k4 * 4 + 1] = t.y;
    wa[k4 * 4 + 2] = t.z; wa[k4 * 4 + 3] = t.w;
  }
  #pragma unroll
  for (int k4 = 0; k4 < 16; ++k4) {
    float4 t = wr[16 + k4];
    wb[k4 * 4 + 0] = t.x; wb[k4 * 4 + 1] = t.y;
    wb[k4 * 4 + 2] = t.z; wb[k4 * 4 + 3] = t.w;
  }
  const float wsl = Ww[lane];
  const float wtl = Ww[64 + lane];

  const int wid = blockIdx.x * (blockDim.x >> 6) + (threadIdx.x >> 6);
  const int nw  = gridDim.x * (blockDim.x >> 6);
  float pmax = -INFINITY, qmax = -INFINITY;
  for (int n = wid; n < N; n += nw) {
    float xl = x[(size_t)n * DID + lane];
    float pp = xl * wsl, qq = xl * wtl;
    #pragma unroll
    for (int o = 32; o >= 1; o >>= 1) {
      pp += __shfl_xor(pp, o);
      qq += __shfl_xor(qq, o);
    }
    pmax = fmaxf(pmax, pp);   // butterfly leaves full sum on every lane
    qmax = fmaxf(qmax, qq);
    float uu = 0.f, vv = 0.f;
    #pragma unroll
    for (int k = 0; k < 64; ++k) {
      float xb = __shfl(xl, k);
      uu = fmaf(xb, wa[k], uu);
      vv = fmaf(xb, wb[k], vv);
    }
    u[(size_t)n * DOD + lane] = uu;
    v[(size_t)n * DOD + lane] = vv;
    if (lane == 0) { p[n] = pp; q[n] = qq; }
  }
  if (lane == 0) {
    atomicMax(&pqmax_key[0], f2key(pmax));
    atomicMax(&pqmax_key[1], f2key(qmax));
  }
}

// ---- kernel 2: degree histogram — streams tgt only (int4) ----
__global__ __launch_bounds__(256) void hist_kernel(
    const int* __restrict__ tgt, int E, int* __restrict__ hist) {
  int tid = blockIdx.x * blockDim.x + threadIdx.x;
  int st  = gridDim.x * blockDim.x;
  int e4  = E >> 2;
  const int4* t4p = (const int4*)tgt;
  for (int i = tid; i < e4; i += st) {
    int4 t4 = t4p[i];
    atomicAdd(&hist[t4.x], 1);
    atomicAdd(&hist[t4.y], 1);
    atomicAdd(&hist[t4.z], 1);
    atomicAdd(&hist[t4.w], 1);
  }
  for (int e = (e4 << 2) + tid; e < E; e += st) atomicAdd(&hist[tgt[e]], 1);
}

// ---- scan (3 kernels): exclusive prefix sum of hist -> rowstart ----
__global__ __launch_bounds__(256) void scan1_kernel(
    const int* __restrict__ hist, int* __restrict__ rowstart,
    int* __restrict__ bsum, int N) {
  int base = blockIdx.x * SCAN_CHUNK + threadIdx.x * 4;
  int h[4]; int ts = 0;
  #pragma unroll
  for (int j = 0; j < 4; ++j) {
    int i = base + j;
    h[j] = (i < N) ? hist[i] : 0;
    ts += h[j];
  }
  int lane = threadIdx.x & 63, wv = threadIdx.x >> 6;
  int sc = ts;
  #pragma unroll
  for (int o = 1; o < 64; o <<= 1) {
    int t = __shfl_up(sc, o);
    if (lane >= o) sc += t;
  }
  __shared__ int wtot[4];
  if (lane == 63) wtot[wv] = sc;
  __syncthreads();
  int woff = 0;
  for (int w = 0; w < wv; ++w) woff += wtot[w];
  int excl = woff + sc - ts;
  #pragma unroll
  for (int j = 0; j < 4; ++j) {
    int i = base + j;
    if (i < N) rowstart[i] = excl;
    excl += h[j];
  }
  if (threadIdx.x == 0) {
    int tot = 0;
    for (int w = 0; w < 4; ++w) tot += wtot[w];
    bsum[blockIdx.x] = tot;
  }
}

__global__ __launch_bounds__(256) void scan2_kernel(int* __restrict__ bsum, int SB) {
  __shared__ int tmp[256];
  int t = threadIdx.x;
  int s = (t < SB) ? bsum[t] : 0;
  tmp[t] = s;
  __syncthreads();
  int acc = s;
  for (int o = 1; o < 256; o <<= 1) {
    int vv = (t >= o) ? tmp[t - o] : 0;
    __syncthreads();
    acc += vv;
    tmp[t] = acc;
    __syncthreads();
  }
  if (t < SB) bsum[t] = acc - s;
}

__global__ __launch_bounds__(256) void scan3_kernel(
    int* __restrict__ rowstart, int* __restrict__ cursor,
    const int* __restrict__ bsum, int N, int E) {
  int base = blockIdx.x * SCAN_CHUNK + threadIdx.x * 4;
  int off = bsum[blockIdx.x];
  #pragma unroll
  for (int j = 0; j < 4; ++j) {
    int i = base + j;
    if (i < N) {
      int r = rowstart[i] + off;
      rowstart[i] = r;
      cursor[i] = r;
    }
  }
  if (blockIdx.x == 0 && threadIdx.x == 0) rowstart[N] = E;
}

// ---- fill: int4 stream, 8 ILP p/q gathers; tracks wmax = exp(amax - M) ----
__global__ __launch_bounds__(256) void fill_kernel(
    const int* __restrict__ src, const int* __restrict__ tgt,
    const float* __restrict__ p, const float* __restrict__ q,
    const unsigned* __restrict__ pqmax_key, int E,
    int* __restrict__ cursor, int2* __restrict__ csr,
    unsigned* __restrict__ wmax_key) {
  const float M = key2f(pqmax_key[0]) + key2f(pqmax_key[1]);
  int tid = blockIdx.x * blockDim.x + threadIdx.x;
  int st  = gridDim.x * blockDim.x;
  int e4  = E >> 2;
  const int4* s4p = (const int4*)src;
  const int4* t4p = (const int4*)tgt;
  float wm = 0.f;
  for (int i = tid; i < e4; i += st) {
    int4 s4 = s4p[i], t4 = t4p[i];
    float a0 = p[s4.x] + q[t4.x];
    float a1 = p[s4.y] + q[t4.y];
    float a2 = p[s4.z] + q[t4.z];
    float a3 = p[s4.w] + q[t4.w];
    float w0 = __expf(a0 - M), w1 = __expf(a1 - M);
    float w2 = __expf(a2 - M), w3 = __expf(a3 - M);
    wm = fmaxf(wm, fmaxf(fmaxf(w0, w1), fmaxf(w2, w3)));
    int p0 = atomicAdd(&cursor[t4.x], 1);
    int p1 = atomicAdd(&cursor[t4.y], 1);
    int p2 = atomicAdd(&cursor[t4.z], 1);
    int p3 = atomicAdd(&cursor[t4.w], 1);
    csr[p0] = make_int2(s4.x, __float_as_int(w0));
    csr[p1] = make_int2(s4.y, __float_as_int(w1));
    csr[p2] = make_int2(s4.z, __float_as_int(w2));
    csr[p3] = make_int2(s4.w, __float_as_int(w3));
  }
  for (int e = (e4 << 2) + tid; e < E; e += st) {
    int t = tgt[e], s = src[e];
    float w = __expf(p[s] + q[t] - M);
    wm = fmaxf(wm, w);
    int pos = atomicAdd(&cursor[t], 1);
    csr[pos] = make_int2(s, __float_as_int(w));
  }
  #pragma unroll
  for (int o = 32; o >= 1; o >>= 1) wm = fmaxf(wm, __shfl_xor(wm, o));
  if ((threadIdx.x & 63) == 0) atomicMax(wmax_key, f2key(wm));
}

// ---- gather: wave per node; coalesced csr batch + shuffle broadcast;
//      4x-unrolled u-row loads; eps*wmax == exact reference eps scaling. ----
__global__ __launch_bounds__(256) void gather_kernel(
    const int* __restrict__ rowstart, const int2* __restrict__ csr,
    const float* __restrict__ u, const float* __restrict__ v,
    const float* __restrict__ bf, const unsigned* __restrict__ wmax_key,
    int N, float* __restrict__ o) {
  const int lane = threadIdx.x & 63;
  const float bfl = bf[lane];
  // w = c*w_ref with c = wmax, so  (c num)/(c den + c eps) == num/(den+eps):
  const float epsEff = 1e-6f * key2f(*wmax_key);
  const int wid = blockIdx.x * (blockDim.x >> 6) + (threadIdx.x >> 6);
  const int nw  = gridDim.x * (blockDim.x >> 6);
  for (int n = wid; n < N; n += nw) {
    const int beg = rowstart[n], end = rowstart[n + 1];
    const float vtl = v[(size_t)n * DOD + lane];
    float acc = 0.f, wl = 0.f;
    for (int bb = beg; bb < end; bb += 64) {
      const int idx = bb + lane;
      int2 c = make_int2(0, 0);               // pad: s=0, w=+0.0f
      if (idx < end) c = csr[idx];            // ONE coalesced 8B/lane load
      float cw = __uint_as_float((unsigned)c.y);
      wl += cw;                                // per-lane partial of Σw
      const int cnt4 = (min(64, end - bb) + 3) & ~3;  // pad edges have w=0
      for (int j = 0; j < cnt4; j += 4) {
        int s0 = __shfl(c.x, j + 0), s1 = __shfl(c.x, j + 1);
        int s2 = __shfl(c.x, j + 2), s3 = __shfl(c.x, j + 3);
        float w0 = __shfl(cw, j + 0), w1 = __shfl(cw, j + 1);
        float w2 = __shfl(cw, j + 2), w3 = __shfl(cw, j + 3);
        float r0 = u[(size_t)s0 * DOD + lane]; // 4 independent 256B gathers
        float r1 = u[(size_t)s1 * DOD + lane];
        float r2 = u[(size_t)s2 * DOD + lane];
        float r3 = u[(size_t)s3 * DOD + lane];
        acc = fmaf(fmaxf(r0 + vtl + bfl, 0.f), w0, acc);
        acc = fmaf(fmaxf(r1 + vtl + bfl, 0.f), w1, acc);
        acc = fmaf(fmaxf(r2 + vtl + bfl, 0.f), w2, acc);
        acc = fmaf(fmaxf(r3 + vtl + bfl, 0.f), w3, acc);
      }
    }
    #pragma unroll
    for (int off = 32; off >= 1; off >>= 1) wl += __shfl_xor(wl, off);
    o[(size_t)n * DOD + lane] = acc / (wl + epsEff);
  }
}

extern "C" void kernel_launch(void* const* d_in, const int* in_sizes, int n_in,
                              void* d_out, int out_size, void* d_ws, size_t ws_size,
                              hipStream_t stream) {
  const float* x  = (const float*)d_in[0];
  const float* Wf = (const float*)d_in[1];
  const float* bf = (const float*)d_in[2];
  const float* Ww = (const float*)d_in[3];
  // d_in[4] = bw: cancels in exp(a - M).
  const int* src = (const int*)d_in[5];
  const int* tgt = (const int*)d_in[6];

  const int N = in_sizes[0] / DID;
  const int E = in_sizes[5];

  // ws: csr[E] int2 | u[N*64] | v[N*64] | p[N] | q[N]
  //     | hist[N] | rowstart[N+1] | cursor[N] | bsum[256]
  //     | pqmax_key[2] | wmax_key[1]
  int2*  csr = (int2*)d_ws;
  float* u   = (float*)(csr + E);
  float* v   = u + (size_t)N * DOD;
  float* p   = v + (size_t)N * DOD;
  float* q   = p + N;
  int* hist     = (int*)(q + N);
  int* rowstart = hist + N;
  int* cursor   = rowstart + N + 1;
  int* bsum     = cursor + N;
  unsigned* pqmax_key = (unsigned*)(bsum + 256);
  unsigned* wmax_key  = pqmax_key + 2;

  hipMemsetAsync(hist, 0, (size_t)N * sizeof(int), stream);
  hipMemsetAsync(pqmax_key, 0, 3 * sizeof(unsigned), stream);

  const int SB = (N + SCAN_CHUNK - 1) / SCAN_CHUNK;

  node_uv_kernel<<<1024, 256, 0, stream>>>(x, Wf, Ww, N, u, v, p, q, pqmax_key);
  hist_kernel<<<1024, 256, 0, stream>>>(tgt, E, hist);
  scan1_kernel<<<SB, 256, 0, stream>>>(hist, rowstart, bsum, N);
  scan2_kernel<<<1, 256, 0, stream>>>(bsum, SB);
  scan3_kernel<<<SB, 256, 0, stream>>>(rowstart, cursor, bsum, N, E);
  fill_kernel<<<1024, 256, 0, stream>>>(src, tgt, p, q, pqmax_key, E, cursor,
                                        csr, wmax_key);
  gather_kernel<<<2048, 256, 0, stream>>>(rowstart, csr, u, v, bf, wmax_key,
                                          N, (float*)d_out);
}

// Round 13
// 435.017 us; speedup vs baseline: 1.6832x; 1.1069x over previous
//
#include <hip/hip_runtime.h>
#include <math.h>

// GATLayerEdgeSoftmax, CSR-gather v4:
//   Same math as v3b (exact eps*wmax compensation). node_uv rewritten as an
//   LDS-tiled register-blocked GEMM: v3b's VGPR-resident W (128 regs) spilled
//   (VGPR_Count=124 < 128) and ran 1 node/wave with 64-deep serial FMA chains
//   -> 156us at 17% VALUBusy. v4: 128-node x 128-out tile/block, transposed
//   LDS staging, 8x8 acc/thread -> ~100 VGPR, 64 indep chains, ~15-25us.

#define DID 64
#define DOD 64
#define SCAN_CHUNK 1024
#define TN 128      // nodes per tile
#define LDA 129     // xT row stride (floats): 2-way-max write conflicts
#define LDB 129     // wT row stride

__device__ __forceinline__ unsigned f2key(float f) {
  unsigned u = __float_as_uint(f);
  return (u & 0x80000000u) ? ~u : (u | 0x80000000u);
}
__device__ __forceinline__ float key2f(unsigned k) {
  unsigned u = (k & 0x80000000u) ? (k ^ 0x80000000u) : ~k;
  return __uint_as_float(u);
}

// ---- kernel 1: node projections as tiled GEMM + p/q + pmax/qmax ----
// out[n][jj] = sum_k x[n][k] * W2[jj][k], W2[j]=Wf[j][:64], W2[64+j]=Wf[j][64:]
// jj<64 -> u, jj>=64 -> v.  p = x.Ww[:64], q = x.Ww[64:].
__global__ __launch_bounds__(256, 2) void node_uv_kernel(
    const float* __restrict__ x, const float* __restrict__ Wf,
    const float* __restrict__ Ww, int N,
    float* __restrict__ u, float* __restrict__ v,
    float* __restrict__ p, float* __restrict__ q,
    unsigned* __restrict__ pqmax_key) {
  __shared__ float xT[64 * LDA];   // xT[k][n]
  __shared__ float wT[64 * LDB];   // wT[k][jj]
  __shared__ float Wsv[128];       // Ww

  const int tid = threadIdx.x;

  // stage W once per block (transposed): Wf[j][c]: c<64 -> wT[c][j],
  // c>=64 -> wT[c-64][64+j]
  {
    const float4* wf4 = (const float4*)Wf;
    for (int f4 = tid; f4 < 64 * 32; f4 += 256) {
      int j = f4 >> 5, c4 = (f4 & 31) << 2;
      float4 t = wf4[f4];
      float tv[4] = {t.x, t.y, t.z, t.w};
      #pragma unroll
      for (int ci = 0; ci < 4; ++ci) {
        int c = c4 + ci;
        int k  = (c < 64) ? c : (c - 64);
        int jj = (c < 64) ? j : (64 + j);
        wT[k * LDB + jj] = tv[ci];
      }
    }
    if (tid < 128) Wsv[tid] = Ww[tid];
  }

  float pmax = -INFINITY, qmax = -INFINITY;

  const int tn = tid >> 4;   // 0..15
  const int tj = tid & 15;   // 0..15
  const int n0 = tn * 8, j0 = tj * 8;
  const int ntiles = (N + TN - 1) / TN;

  for (int tile = blockIdx.x; tile < ntiles; tile += gridDim.x) {
    const int base = tile * TN;
    __syncthreads();   // covers W-stage (first iter) + prior-iter LDS reads
    // stage xT[k][n] = x[base+n][k], zero-pad beyond N
    {
      const float4* x4 = (const float4*)(x + (size_t)base * DID);
      for (int f4 = tid; f4 < TN * 16; f4 += 256) {
        int n = f4 >> 4, k4 = (f4 & 15) << 2;
        float4 t = (base + n < N) ? x4[f4] : make_float4(0.f, 0.f, 0.f, 0.f);
        xT[(k4 + 0) * LDA + n] = t.x;
        xT[(k4 + 1) * LDA + n] = t.y;
        xT[(k4 + 2) * LDA + n] = t.z;
        xT[(k4 + 3) * LDA + n] = t.w;
      }
    }
    __syncthreads();

    float acc[8][8];
    #pragma unroll
    for (int i = 0; i < 8; ++i)
      #pragma unroll
      for (int jx = 0; jx < 8; ++jx) acc[i][jx] = 0.f;

    #pragma unroll 4
    for (int k = 0; k < 64; ++k) {
      float4 a0 = *(const float4*)&xT[k * LDA + n0];
      float4 a1 = *(const float4*)&xT[k * LDA + n0 + 4];
      float4 b0 = *(const float4*)&wT[k * LDB + j0];
      float4 b1 = *(const float4*)&wT[k * LDB + j0 + 4];
      float av[8] = {a0.x, a0.y, a0.z, a0.w, a1.x, a1.y, a1.z, a1.w};
      float bv[8] = {b0.x, b0.y, b0.z, b0.w, b1.x, b1.y, b1.z, b1.w};
      #pragma unroll
      for (int i = 0; i < 8; ++i)
        #pragma unroll
        for (int jx = 0; jx < 8; ++jx)
          acc[i][jx] = fmaf(av[i], bv[jx], acc[i][jx]);
    }

    // store 8 rows x 8 cols; j0 block lies fully in u (j0<64) or v
    #pragma unroll
    for (int i = 0; i < 8; ++i) {
      int n = base + n0 + i;
      if (n < N) {
        float* dst = (j0 < 64) ? (u + (size_t)n * DOD + j0)
                               : (v + (size_t)n * DOD + (j0 - 64));
        *(float4*)dst       = make_float4(acc[i][0], acc[i][1], acc[i][2], acc[i][3]);
        *(float4*)(dst + 4) = make_float4(acc[i][4], acc[i][5], acc[i][6], acc[i][7]);
      }
    }

    // p,q for this tile (threads 0..127, one node each), from staged xT
    if (tid < TN) {
      int n = base + tid;
      if (n < N) {
        float pp = 0.f, qq = 0.f;
        #pragma unroll 8
        for (int k = 0; k < 64; ++k) {
          float xv = xT[k * LDA + tid];
          pp = fmaf(xv, Wsv[k], pp);
          qq = fmaf(xv, Wsv[64 + k], qq);
        }
        p[n] = pp; q[n] = qq;
        pmax = fmaxf(pmax, pp); qmax = fmaxf(qmax, qq);
      }
    }
  }

  #pragma unroll
  for (int o = 32; o >= 1; o >>= 1) {
    pmax = fmaxf(pmax, __shfl_xor(pmax, o));
    qmax = fmaxf(qmax, __shfl_xor(qmax, o));
  }
  if ((tid & 63) == 0) {
    atomicMax(&pqmax_key[0], f2key(pmax));
    atomicMax(&pqmax_key[1], f2key(qmax));
  }
}

// ---- kernel 2: degree histogram — streams tgt only (int4) ----
__global__ __launch_bounds__(256) void hist_kernel(
    const int* __restrict__ tgt, int E, int* __restrict__ hist) {
  int tid = blockIdx.x * blockDim.x + threadIdx.x;
  int st  = gridDim.x * blockDim.x;
  int e4  = E >> 2;
  const int4* t4p = (const int4*)tgt;
  for (int i = tid; i < e4; i += st) {
    int4 t4 = t4p[i];
    atomicAdd(&hist[t4.x], 1);
    atomicAdd(&hist[t4.y], 1);
    atomicAdd(&hist[t4.z], 1);
    atomicAdd(&hist[t4.w], 1);
  }
  for (int e = (e4 << 2) + tid; e < E; e += st) atomicAdd(&hist[tgt[e]], 1);
}

// ---- scan (3 kernels): exclusive prefix sum of hist -> rowstart ----
__global__ __launch_bounds__(256) void scan1_kernel(
    const int* __restrict__ hist, int* __restrict__ rowstart,
    int* __restrict__ bsum, int N) {
  int base = blockIdx.x * SCAN_CHUNK + threadIdx.x * 4;
  int h[4]; int ts = 0;
  #pragma unroll
  for (int j = 0; j < 4; ++j) {
    int i = base + j;
    h[j] = (i < N) ? hist[i] : 0;
    ts += h[j];
  }
  int lane = threadIdx.x & 63, wv = threadIdx.x >> 6;
  int sc = ts;
  #pragma unroll
  for (int o = 1; o < 64; o <<= 1) {
    int t = __shfl_up(sc, o);
    if (lane >= o) sc += t;
  }
  __shared__ int wtot[4];
  if (lane == 63) wtot[wv] = sc;
  __syncthreads();
  int woff = 0;
  for (int w = 0; w < wv; ++w) woff += wtot[w];
  int excl = woff + sc - ts;
  #pragma unroll
  for (int j = 0; j < 4; ++j) {
    int i = base + j;
    if (i < N) rowstart[i] = excl;
    excl += h[j];
  }
  if (threadIdx.x == 0) {
    int tot = 0;
    for (int w = 0; w < 4; ++w) tot += wtot[w];
    bsum[blockIdx.x] = tot;
  }
}

__global__ __launch_bounds__(256) void scan2_kernel(int* __restrict__ bsum, int SB) {
  __shared__ int tmp[256];
  int t = threadIdx.x;
  int s = (t < SB) ? bsum[t] : 0;
  tmp[t] = s;
  __syncthreads();
  int acc = s;
  for (int o = 1; o < 256; o <<= 1) {
    int vv = (t >= o) ? tmp[t - o] : 0;
    __syncthreads();
    acc += vv;
    tmp[t] = acc;
    __syncthreads();
  }
  if (t < SB) bsum[t] = acc - s;
}

__global__ __launch_bounds__(256) void scan3_kernel(
    int* __restrict__ rowstart, int* __restrict__ cursor,
    const int* __restrict__ bsum, int N, int E) {
  int base = blockIdx.x * SCAN_CHUNK + threadIdx.x * 4;
  int off = bsum[blockIdx.x];
  #pragma unroll
  for (int j = 0; j < 4; ++j) {
    int i = base + j;
    if (i < N) {
      int r = rowstart[i] + off;
      rowstart[i] = r;
      cursor[i] = r;
    }
  }
  if (blockIdx.x == 0 && threadIdx.x == 0) rowstart[N] = E;
}

// ---- fill: int4 stream, 8 ILP p/q gathers; tracks wmax = exp(amax - M) ----
__global__ __launch_bounds__(256) void fill_kernel(
    const int* __restrict__ src, const int* __restrict__ tgt,
    const float* __restrict__ p, const float* __restrict__ q,
    const unsigned* __restrict__ pqmax_key, int E,
    int* __restrict__ cursor, int2* __restrict__ csr,
    unsigned* __restrict__ wmax_key) {
  const float M = key2f(pqmax_key[0]) + key2f(pqmax_key[1]);
  int tid = blockIdx.x * blockDim.x + threadIdx.x;
  int st  = gridDim.x * blockDim.x;
  int e4  = E >> 2;
  const int4* s4p = (const int4*)src;
  const int4* t4p = (const int4*)tgt;
  float wm = 0.f;
  for (int i = tid; i < e4; i += st) {
    int4 s4 = s4p[i], t4 = t4p[i];
    float a0 = p[s4.x] + q[t4.x];
    float a1 = p[s4.y] + q[t4.y];
    float a2 = p[s4.z] + q[t4.z];
    float a3 = p[s4.w] + q[t4.w];
    float w0 = __expf(a0 - M), w1 = __expf(a1 - M);
    float w2 = __expf(a2 - M), w3 = __expf(a3 - M);
    wm = fmaxf(wm, fmaxf(fmaxf(w0, w1), fmaxf(w2, w3)));
    int p0 = atomicAdd(&cursor[t4.x], 1);
    int p1 = atomicAdd(&cursor[t4.y], 1);
    int p2 = atomicAdd(&cursor[t4.z], 1);
    int p3 = atomicAdd(&cursor[t4.w], 1);
    csr[p0] = make_int2(s4.x, __float_as_int(w0));
    csr[p1] = make_int2(s4.y, __float_as_int(w1));
    csr[p2] = make_int2(s4.z, __float_as_int(w2));
    csr[p3] = make_int2(s4.w, __float_as_int(w3));
  }
  for (int e = (e4 << 2) + tid; e < E; e += st) {
    int t = tgt[e], s = src[e];
    float w = __expf(p[s] + q[t] - M);
    wm = fmaxf(wm, w);
    int pos = atomicAdd(&cursor[t], 1);
    csr[pos] = make_int2(s, __float_as_int(w));
  }
  #pragma unroll
  for (int o = 32; o >= 1; o >>= 1) wm = fmaxf(wm, __shfl_xor(wm, o));
  if ((threadIdx.x & 63) == 0) atomicMax(wmax_key, f2key(wm));
}

// ---- gather: wave per node; coalesced csr batch + shuffle broadcast;
//      4x-unrolled u-row loads; eps*wmax == exact reference eps scaling. ----
__global__ __launch_bounds__(256) void gather_kernel(
    const int* __restrict__ rowstart, const int2* __restrict__ csr,
    const float* __restrict__ u, const float* __restrict__ v,
    const float* __restrict__ bf, const unsigned* __restrict__ wmax_key,
    int N, float* __restrict__ o) {
  const int lane = threadIdx.x & 63;
  const float bfl = bf[lane];
  // w = c*w_ref with c = wmax, so  (c num)/(c den + c eps) == num/(den+eps):
  const float epsEff = 1e-6f * key2f(*wmax_key);
  const int wid = blockIdx.x * (blockDim.x >> 6) + (threadIdx.x >> 6);
  const int nw  = gridDim.x * (blockDim.x >> 6);
  for (int n = wid; n < N; n += nw) {
    const int beg = rowstart[n], end = rowstart[n + 1];
    const float vtl = v[(size_t)n * DOD + lane];
    float acc = 0.f, wl = 0.f;
    for (int bb = beg; bb < end; bb += 64) {
      const int idx = bb + lane;
      int2 c = make_int2(0, 0);               // pad: s=0, w=+0.0f
      if (idx < end) c = csr[idx];            // ONE coalesced 8B/lane load
      float cw = __uint_as_float((unsigned)c.y);
      wl += cw;                                // per-lane partial of Σw
      const int cnt4 = (min(64, end - bb) + 3) & ~3;  // pad edges have w=0
      for (int j = 0; j < cnt4; j += 4) {
        int s0 = __shfl(c.x, j + 0), s1 = __shfl(c.x, j + 1);
        int s2 = __shfl(c.x, j + 2), s3 = __shfl(c.x, j + 3);
        float w0 = __shfl(cw, j + 0), w1 = __shfl(cw, j + 1);
        float w2 = __shfl(cw, j + 2), w3 = __shfl(cw, j + 3);
        float r0 = u[(size_t)s0 * DOD + lane]; // 4 independent 256B gathers
        float r1 = u[(size_t)s1 * DOD + lane];
        float r2 = u[(size_t)s2 * DOD + lane];
        float r3 = u[(size_t)s3 * DOD + lane];
        acc = fmaf(fmaxf(r0 + vtl + bfl, 0.f), w0, acc);
        acc = fmaf(fmaxf(r1 + vtl + bfl, 0.f), w1, acc);
        acc = fmaf(fmaxf(r2 + vtl + bfl, 0.f), w2, acc);
        acc = fmaf(fmaxf(r3 + vtl + bfl, 0.f), w3, acc);
      }
    }
    #pragma unroll
    for (int off = 32; off >= 1; off >>= 1) wl += __shfl_xor(wl, off);
    o[(size_t)n * DOD + lane] = acc / (wl + epsEff);
  }
}

extern "C" void kernel_launch(void* const* d_in, const int* in_sizes, int n_in,
                              void* d_out, int out_size, void* d_ws, size_t ws_size,
                              hipStream_t stream) {
  const float* x  = (const float*)d_in[0];
  const float* Wf = (const float*)d_in[1];
  const float* bf = (const float*)d_in[2];
  const float* Ww = (const float*)d_in[3];
  // d_in[4] = bw: cancels in exp(a - M).
  const int* src = (const int*)d_in[5];
  const int* tgt = (const int*)d_in[6];

  const int N = in_sizes[0] / DID;
  const int E = in_sizes[5];

  // ws: csr[E] int2 | u[N*64] | v[N*64] | p[N] | q[N]
  //     | hist[N] | rowstart[N+1] | cursor[N] | bsum[256]
  //     | pqmax_key[2] | wmax_key[1]
  int2*  csr = (int2*)d_ws;
  float* u   = (float*)(csr + E);
  float* v   = u + (size_t)N * DOD;
  float* p   = v + (size_t)N * DOD;
  float* q   = p + N;
  int* hist     = (int*)(q + N);
  int* rowstart = hist + N;
  int* cursor   = rowstart + N + 1;
  int* bsum     = cursor + N;
  unsigned* pqmax_key = (unsigned*)(bsum + 256);
  unsigned* wmax_key  = pqmax_key + 2;

  hipMemsetAsync(hist, 0, (size_t)N * sizeof(int), stream);
  hipMemsetAsync(pqmax_key, 0, 3 * sizeof(unsigned), stream);

  const int SB = (N + SCAN_CHUNK - 1) / SCAN_CHUNK;
  const int ntiles = (N + TN - 1) / TN;

  node_uv_kernel<<<ntiles, 256, 0, stream>>>(x, Wf, Ww, N, u, v, p, q, pqmax_key);
  hist_kernel<<<1024, 256, 0, stream>>>(tgt, E, hist);
  scan1_kernel<<<SB, 256, 0, stream>>>(hist, rowstart, bsum, N);
  scan2_kernel<<<1, 256, 0, stream>>>(bsum, SB);
  scan3_kernel<<<SB, 256, 0, stream>>>(rowstart, cursor, bsum, N, E);
  fill_kernel<<<1024, 256, 0, stream>>>(src, tgt, p, q, pqmax_key, E, cursor,
                                        csr, wmax_key);
  gather_kernel<<<2048, 256, 0, stream>>>(rowstart, csr, u, v, bf, wmax_key,
                                          N, (float*)d_out);
}

// Round 15
// 387.194 us; speedup vs baseline: 1.8910x; 1.1235x over previous
//
#include <hip/hip_runtime.h>
#include <math.h>

// GATLayerEdgeSoftmax, CSR-gather v5:
//   Math identical to v3b/v4 (exact eps*wmax compensation).
//   v4 profile: fill = 110us, VALUBusy 0.95%, WRITE_SIZE 102MB = 64B/edge
//   -> scattered int2 CSR writes pay full-line evictions. v5:
//   (1) CSR stores src only (4B); gather recomputes w = exp(p[s]+q[t]-M)
//       (p is L2-resident, exp is free) -> half the dirty lines.
//   (2) tgt-histogram merged into node_uv as an independent grid-stride
//       phase (memory-bound hist overlaps compute-bound GEMM, -1 launch).

#define DID 64
#define DOD 64
#define SCAN_CHUNK 1024
#define TN 128      // nodes per tile
#define LDA 129     // xT row stride (floats)
#define LDB 129     // wT row stride

__device__ __forceinline__ unsigned f2key(float f) {
  unsigned u = __float_as_uint(f);
  return (u & 0x80000000u) ? ~u : (u | 0x80000000u);
}
__device__ __forceinline__ float key2f(unsigned k) {
  unsigned u = (k & 0x80000000u) ? (k ^ 0x80000000u) : ~k;
  return __uint_as_float(u);
}

// ---- kernel 1: tiled-GEMM node projections + p/q + pmax/qmax,
//      then (independent) grid-stride tgt histogram ----
__global__ __launch_bounds__(256, 2) void node_uv_kernel(
    const float* __restrict__ x, const float* __restrict__ Wf,
    const float* __restrict__ Ww, int N,
    float* __restrict__ u, float* __restrict__ v,
    float* __restrict__ p, float* __restrict__ q,
    unsigned* __restrict__ pqmax_key,
    const int* __restrict__ tgt, int E, int* __restrict__ hist) {
  __shared__ float xT[64 * LDA];   // xT[k][n]
  __shared__ float wT[64 * LDB];   // wT[k][jj]
  __shared__ float Wsv[128];       // Ww

  const int tid = threadIdx.x;

  // stage W once per block (transposed)
  {
    const float4* wf4 = (const float4*)Wf;
    for (int f4 = tid; f4 < 64 * 32; f4 += 256) {
      int j = f4 >> 5, c4 = (f4 & 31) << 2;
      float4 t = wf4[f4];
      float tv[4] = {t.x, t.y, t.z, t.w};
      #pragma unroll
      for (int ci = 0; ci < 4; ++ci) {
        int c = c4 + ci;
        int k  = (c < 64) ? c : (c - 64);
        int jj = (c < 64) ? j : (64 + j);
        wT[k * LDB + jj] = tv[ci];
      }
    }
    if (tid < 128) Wsv[tid] = Ww[tid];
  }

  float pmax = -INFINITY, qmax = -INFINITY;

  const int tn = tid >> 4;
  const int tj = tid & 15;
  const int n0 = tn * 8, j0 = tj * 8;
  const int ntiles = (N + TN - 1) / TN;

  for (int tile = blockIdx.x; tile < ntiles; tile += gridDim.x) {
    const int base = tile * TN;
    __syncthreads();   // covers W-stage (first iter) + prior-iter LDS reads
    {
      const float4* x4 = (const float4*)(x + (size_t)base * DID);
      for (int f4 = tid; f4 < TN * 16; f4 += 256) {
        int n = f4 >> 4, k4 = (f4 & 15) << 2;
        float4 t = (base + n < N) ? x4[f4] : make_float4(0.f, 0.f, 0.f, 0.f);
        xT[(k4 + 0) * LDA + n] = t.x;
        xT[(k4 + 1) * LDA + n] = t.y;
        xT[(k4 + 2) * LDA + n] = t.z;
        xT[(k4 + 3) * LDA + n] = t.w;
      }
    }
    __syncthreads();

    float acc[8][8];
    #pragma unroll
    for (int i = 0; i < 8; ++i)
      #pragma unroll
      for (int jx = 0; jx < 8; ++jx) acc[i][jx] = 0.f;

    #pragma unroll 4
    for (int k = 0; k < 64; ++k) {
      float4 a0 = *(const float4*)&xT[k * LDA + n0];
      float4 a1 = *(const float4*)&xT[k * LDA + n0 + 4];
      float4 b0 = *(const float4*)&wT[k * LDB + j0];
      float4 b1 = *(const float4*)&wT[k * LDB + j0 + 4];
      float av[8] = {a0.x, a0.y, a0.z, a0.w, a1.x, a1.y, a1.z, a1.w};
      float bv[8] = {b0.x, b0.y, b0.z, b0.w, b1.x, b1.y, b1.z, b1.w};
      #pragma unroll
      for (int i = 0; i < 8; ++i)
        #pragma unroll
        for (int jx = 0; jx < 8; ++jx)
          acc[i][jx] = fmaf(av[i], bv[jx], acc[i][jx]);
    }

    #pragma unroll
    for (int i = 0; i < 8; ++i) {
      int n = base + n0 + i;
      if (n < N) {
        float* dst = (j0 < 64) ? (u + (size_t)n * DOD + j0)
                               : (v + (size_t)n * DOD + (j0 - 64));
        *(float4*)dst       = make_float4(acc[i][0], acc[i][1], acc[i][2], acc[i][3]);
        *(float4*)(dst + 4) = make_float4(acc[i][4], acc[i][5], acc[i][6], acc[i][7]);
      }
    }

    if (tid < TN) {
      int n = base + tid;
      if (n < N) {
        float pp = 0.f, qq = 0.f;
        #pragma unroll 8
        for (int k = 0; k < 64; ++k) {
          float xv = xT[k * LDA + tid];
          pp = fmaf(xv, Wsv[k], pp);
          qq = fmaf(xv, Wsv[64 + k], qq);
        }
        p[n] = pp; q[n] = qq;
        pmax = fmaxf(pmax, pp); qmax = fmaxf(qmax, qq);
      }
    }
  }

  #pragma unroll
  for (int o = 32; o >= 1; o >>= 1) {
    pmax = fmaxf(pmax, __shfl_xor(pmax, o));
    qmax = fmaxf(qmax, __shfl_xor(qmax, o));
  }
  if ((tid & 63) == 0) {
    atomicMax(&pqmax_key[0], f2key(pmax));
    atomicMax(&pqmax_key[1], f2key(qmax));
  }

  // ---- phase 2: tgt histogram (no dependency on phase 1) ----
  {
    int gtid = blockIdx.x * blockDim.x + tid;
    int gst  = gridDim.x * blockDim.x;
    int e4   = E >> 2;
    const int4* t4p = (const int4*)tgt;
    for (int i = gtid; i < e4; i += gst) {
      int4 t4 = t4p[i];
      atomicAdd(&hist[t4.x], 1);
      atomicAdd(&hist[t4.y], 1);
      atomicAdd(&hist[t4.z], 1);
      atomicAdd(&hist[t4.w], 1);
    }
    for (int e = (e4 << 2) + gtid; e < E; e += gst) atomicAdd(&hist[tgt[e]], 1);
  }
}

// ---- scan (3 kernels): exclusive prefix sum of hist -> rowstart ----
__global__ __launch_bounds__(256) void scan1_kernel(
    const int* __restrict__ hist, int* __restrict__ rowstart,
    int* __restrict__ bsum, int N) {
  int base = blockIdx.x * SCAN_CHUNK + threadIdx.x * 4;
  int h[4]; int ts = 0;
  #pragma unroll
  for (int j = 0; j < 4; ++j) {
    int i = base + j;
    h[j] = (i < N) ? hist[i] : 0;
    ts += h[j];
  }
  int lane = threadIdx.x & 63, wv = threadIdx.x >> 6;
  int sc = ts;
  #pragma unroll
  for (int o = 1; o < 64; o <<= 1) {
    int t = __shfl_up(sc, o);
    if (lane >= o) sc += t;
  }
  __shared__ int wtot[4];
  if (lane == 63) wtot[wv] = sc;
  __syncthreads();
  int woff = 0;
  for (int w = 0; w < wv; ++w) woff += wtot[w];
  int excl = woff + sc - ts;
  #pragma unroll
  for (int j = 0; j < 4; ++j) {
    int i = base + j;
    if (i < N) rowstart[i] = excl;
    excl += h[j];
  }
  if (threadIdx.x == 0) {
    int tot = 0;
    for (int w = 0; w < 4; ++w) tot += wtot[w];
    bsum[blockIdx.x] = tot;
  }
}

__global__ __launch_bounds__(256) void scan2_kernel(int* __restrict__ bsum, int SB) {
  __shared__ int tmp[256];
  int t = threadIdx.x;
  int s = (t < SB) ? bsum[t] : 0;
  tmp[t] = s;
  __syncthreads();
  int acc = s;
  for (int o = 1; o < 256; o <<= 1) {
    int vv = (t >= o) ? tmp[t - o] : 0;
    __syncthreads();
    acc += vv;
    tmp[t] = acc;
    __syncthreads();
  }
  if (t < SB) bsum[t] = acc - s;
}

__global__ __launch_bounds__(256) void scan3_kernel(
    int* __restrict__ rowstart, int* __restrict__ cursor,
    const int* __restrict__ bsum, int N, int E) {
  int base = blockIdx.x * SCAN_CHUNK + threadIdx.x * 4;
  int off = bsum[blockIdx.x];
  #pragma unroll
  for (int j = 0; j < 4; ++j) {
    int i = base + j;
    if (i < N) {
      int r = rowstart[i] + off;
      rowstart[i] = r;
      cursor[i] = r;
    }
  }
  if (blockIdx.x == 0 && threadIdx.x == 0) rowstart[N] = E;
}

// ---- fill: scatter src-only (4B) into CSR; exp kept just for wmax ----
__global__ __launch_bounds__(256) void fill_kernel(
    const int* __restrict__ src, const int* __restrict__ tgt,
    const float* __restrict__ p, const float* __restrict__ q,
    const unsigned* __restrict__ pqmax_key, int E,
    int* __restrict__ cursor, int* __restrict__ csr_src,
    unsigned* __restrict__ wmax_key) {
  const float M = key2f(pqmax_key[0]) + key2f(pqmax_key[1]);
  int tid = blockIdx.x * blockDim.x + threadIdx.x;
  int st  = gridDim.x * blockDim.x;
  int e4  = E >> 2;
  const int4* s4p = (const int4*)src;
  const int4* t4p = (const int4*)tgt;
  float wm = 0.f;
  for (int i = tid; i < e4; i += st) {
    int4 s4 = s4p[i], t4 = t4p[i];
    float a0 = p[s4.x] + q[t4.x];
    float a1 = p[s4.y] + q[t4.y];
    float a2 = p[s4.z] + q[t4.z];
    float a3 = p[s4.w] + q[t4.w];
    wm = fmaxf(wm, fmaxf(fmaxf(a0, a1), fmaxf(a2, a3)));
    int p0 = atomicAdd(&cursor[t4.x], 1);
    int p1 = atomicAdd(&cursor[t4.y], 1);
    int p2 = atomicAdd(&cursor[t4.z], 1);
    int p3 = atomicAdd(&cursor[t4.w], 1);
    csr_src[p0] = s4.x;
    csr_src[p1] = s4.y;
    csr_src[p2] = s4.z;
    csr_src[p3] = s4.w;
  }
  for (int e = (e4 << 2) + tid; e < E; e += st) {
    int t = tgt[e], s = src[e];
    wm = fmaxf(wm, p[s] + q[t]);
    int pos = atomicAdd(&cursor[t], 1);
    csr_src[pos] = s;
  }
  // wm currently = max(a); convert to wmax = exp(amax - M) at the end
  #pragma unroll
  for (int o = 32; o >= 1; o >>= 1) wm = fmaxf(wm, __shfl_xor(wm, o));
  if ((threadIdx.x & 63) == 0) atomicMax(wmax_key, f2key(__expf(wm - M)));
}

// ---- gather: wave per node; coalesced 4B csr batch; per-lane p-gather +
//      exp; shuffle broadcast; 4x-unrolled u-row loads; eps*wmax. ----
__global__ __launch_bounds__(256) void gather_kernel(
    const int* __restrict__ rowstart, const int* __restrict__ csr_src,
    const float* __restrict__ p, const float* __restrict__ q,
    const float* __restrict__ u, const float* __restrict__ v,
    const float* __restrict__ bf, const unsigned* __restrict__ pqmax_key,
    const unsigned* __restrict__ wmax_key,
    int N, float* __restrict__ o) {
  const int lane = threadIdx.x & 63;
  const float bfl = bf[lane];
  const float M = key2f(pqmax_key[0]) + key2f(pqmax_key[1]);
  // w = c*w_ref with c = wmax, so (c num)/(c den + c eps) == num/(den+eps):
  const float epsEff = 1e-6f * key2f(*wmax_key);
  const int wid = blockIdx.x * (blockDim.x >> 6) + (threadIdx.x >> 6);
  const int nw  = gridDim.x * (blockDim.x >> 6);
  for (int n = wid; n < N; n += nw) {
    const int beg = rowstart[n], end = rowstart[n + 1];
    const float vtl = v[(size_t)n * DOD + lane];
    const float qn  = q[n];                   // uniform scalar
    float acc = 0.f, wl = 0.f;
    for (int bb = beg; bb < end; bb += 64) {
      const int idx = bb + lane;
      int se = (idx < end) ? csr_src[idx] : 0;   // ONE coalesced 4B/lane load
      float cw = (idx < end) ? __expf(p[se] + qn - M) : 0.f;  // L2 p-gather
      wl += cw;                                // per-lane partial of Σw
      const int cnt4 = (min(64, end - bb) + 3) & ~3;  // pad edges have w=0
      for (int j = 0; j < cnt4; j += 4) {
        int s0 = __shfl(se, j + 0), s1 = __shfl(se, j + 1);
        int s2 = __shfl(se, j + 2), s3 = __shfl(se, j + 3);
        float w0 = __shfl(cw, j + 0), w1 = __shfl(cw, j + 1);
        float w2 = __shfl(cw, j + 2), w3 = __shfl(cw, j + 3);
        float r0 = u[(size_t)s0 * DOD + lane]; // 4 independent 256B gathers
        float r1 = u[(size_t)s1 * DOD + lane];
        float r2 = u[(size_t)s2 * DOD + lane];
        float r3 = u[(size_t)s3 * DOD + lane];
        acc = fmaf(fmaxf(r0 + vtl + bfl, 0.f), w0, acc);
        acc = fmaf(fmaxf(r1 + vtl + bfl, 0.f), w1, acc);
        acc = fmaf(fmaxf(r2 + vtl + bfl, 0.f), w2, acc);
        acc = fmaf(fmaxf(r3 + vtl + bfl, 0.f), w3, acc);
      }
    }
    #pragma unroll
    for (int off = 32; off >= 1; off >>= 1) wl += __shfl_xor(wl, off);
    o[(size_t)n * DOD + lane] = acc / (wl + epsEff);
  }
}

extern "C" void kernel_launch(void* const* d_in, const int* in_sizes, int n_in,
                              void* d_out, int out_size, void* d_ws, size_t ws_size,
                              hipStream_t stream) {
  const float* x  = (const float*)d_in[0];
  const float* Wf = (const float*)d_in[1];
  const float* bf = (const float*)d_in[2];
  const float* Ww = (const float*)d_in[3];
  // d_in[4] = bw: cancels in exp(a - M).
  const int* src = (const int*)d_in[5];
  const int* tgt = (const int*)d_in[6];

  const int N = in_sizes[0] / DID;
  const int E = in_sizes[5];

  // ws: csr_src[E] int | u[N*64] | v[N*64] | p[N] | q[N]
  //     | hist[N] | rowstart[N+1] | cursor[N] | bsum[256]
  //     | pqmax_key[2] | wmax_key[1]
  int*   csr_src = (int*)d_ws;
  float* u   = (float*)(csr_src + E);
  float* v   = u + (size_t)N * DOD;
  float* p   = v + (size_t)N * DOD;
  float* q   = p + N;
  int* hist     = (int*)(q + N);
  int* rowstart = hist + N;
  int* cursor   = rowstart + N + 1;
  int* bsum     = cursor + N;
  unsigned* pqmax_key = (unsigned*)(bsum + 256);
  unsigned* wmax_key  = pqmax_key + 2;

  hipMemsetAsync(hist, 0, (size_t)N * sizeof(int), stream);
  hipMemsetAsync(pqmax_key, 0, 3 * sizeof(unsigned), stream);

  const int SB = (N + SCAN_CHUNK - 1) / SCAN_CHUNK;
  const int ntiles = (N + TN - 1) / TN;

  node_uv_kernel<<<ntiles, 256, 0, stream>>>(x, Wf, Ww, N, u, v, p, q,
                                             pqmax_key, tgt, E, hist);
  scan1_kernel<<<SB, 256, 0, stream>>>(hist, rowstart, bsum, N);
  scan2_kernel<<<1, 256, 0, stream>>>(bsum, SB);
  scan3_kernel<<<SB, 256, 0, stream>>>(rowstart, cursor, bsum, N, E);
  fill_kernel<<<1024, 256, 0, stream>>>(src, tgt, p, q, pqmax_key, E, cursor,
                                        csr_src, wmax_key);
  gather_kernel<<<2048, 256, 0, stream>>>(rowstart, csr_src, p, q, u, v, bf,
                                          pqmax_key, wmax_key, N, (float*)d_out);
}